// Round 2
// baseline (1704.537 us; speedup 1.0000x reference)
//
#include <hip/hip_runtime.h>
#include <hip/hip_bf16.h>
#include <math.h>

#define DD 64
#define CAP 64
#define GG 1024   // fixed grid for partial-reduction kernels

// ---------------- bucket build: incoming-edge lists per node ----------------
__global__ void place_kernel(const int* __restrict__ row, const int* __restrict__ col,
                             int* __restrict__ bucket, int* __restrict__ cnt, int E) {
    int e = blockIdx.x * blockDim.x + threadIdx.x;
    if (e >= E) return;
    int r = row[e], c = col[e];
    int pos = atomicAdd(&cnt[c], 1);
    if (pos < CAP) bucket[(size_t)c * CAP + pos] = r;
}

__global__ void dis_kernel(const int* __restrict__ cnt, float* __restrict__ dis, int n) {
    int v = blockIdx.x * blockDim.x + threadIdx.x;
    if (v >= n) return;
    dis[v] = rsqrtf((float)cnt[v] + 1.0f);   // deg = in-count + self loop
}

// ---------------- GEMM: out[v,:] = X[src(v),:] @ W  (64x64) ----------------
__global__ void gemm64(const float* __restrict__ X, const float* __restrict__ W,
                       float* __restrict__ out, const int* __restrict__ perm, int n) {
    __shared__ float Wt[64 * 64];            // W^T: Wt[j][k] = W[k][j]
    for (int i = threadIdx.x; i < 64 * 64; i += blockDim.x) {
        int k = i >> 6, j = i & 63;
        Wt[j * 64 + k] = W[i];
    }
    __syncthreads();
    int v = blockIdx.x * blockDim.x + threadIdx.x;
    if (v >= n) return;
    int src = perm ? perm[v] : v;
    const float4* xr = (const float4*)(X + (size_t)src * 64);
    float4 xv[16];
#pragma unroll
    for (int i = 0; i < 16; i++) xv[i] = xr[i];
    float* op = out + (size_t)v * 64;
#pragma unroll 4
    for (int j = 0; j < 64; j++) {
        const float4* wr = (const float4*)&Wt[j * 64];
        float a0 = 0.f, a1 = 0.f, a2 = 0.f, a3 = 0.f;
#pragma unroll
        for (int k = 0; k < 16; k++) {
            float4 w4 = wr[k], x4 = xv[k];
            a0 += x4.x * w4.x;
            a1 += x4.y * w4.y;
            a2 += x4.z * w4.z;
            a3 += x4.w * w4.w;
        }
        op[j] = (a0 + a1) + (a2 + a3);
    }
}

// ---------------- fused GCN aggregation (wave per node, lane = dim) --------
// MODE 0: relu(agg + self + bias) -> out
// MODE 1: (agg + self + bias) -> out, accumulate per-block column partials
// MODE 2: z computed on the fly, p = z . ws, accumulate -log(sigmoid(-p)+eps)
template <int MODE>
__global__ void conv_kernel(const float* __restrict__ h, const int* __restrict__ bucket,
                            const int* __restrict__ cnt, const float* __restrict__ dis,
                            const float* __restrict__ bias, float* __restrict__ out,
                            const float* __restrict__ wsv, float* __restrict__ colpart,
                            float* __restrict__ lossacc, int n) {
    int lane = threadIdx.x & 63;
    int wid  = threadIdx.x >> 6;
    int wpb  = blockDim.x >> 6;
    __shared__ float s[256];
    float colp = 0.f;
    float lsum = 0.f;
    float blane = bias[lane];
    float wlane = (MODE == 2) ? wsv[lane] : 0.f;

    for (int v = blockIdx.x * wpb + wid; v < n; v += gridDim.x * wpb) {
        int c = cnt[v];
        if (c > CAP) c = CAP;
        float dv  = dis[v];
        float acc = h[(size_t)v * 64 + lane] * (dv * dv);   // self-loop term
        const int* bk = bucket + (size_t)v * CAP;
        for (int i = 0; i < c; i++) {
            int r = bk[i];
            acc += h[(size_t)r * 64 + lane] * (dis[r] * dv);
        }
        acc += blane;
        if (MODE == 0) {
            out[(size_t)v * 64 + lane] = fmaxf(acc, 0.f);
        } else if (MODE == 1) {
            out[(size_t)v * 64 + lane] = acc;
            colp += acc;
        } else {
            float p = acc * wlane;
            for (int off = 32; off; off >>= 1) p += __shfl_xor(p, off, 64);
            if (lane == 0) lsum += -logf(1.f / (1.f + expf(p)) + 1e-15f);
        }
    }

    if (MODE == 1) {
        s[wid * 64 + lane] = colp;
        __syncthreads();
        if (wid == 0) {
            float t = s[lane];
            for (int w = 1; w < wpb; w++) t += s[w * 64 + lane];
            colpart[(size_t)blockIdx.x * 64 + lane] = t;
        }
    } else if (MODE == 2) {
        if (lane == 0) s[wid] = lsum;
        __syncthreads();
        if (threadIdx.x == 0) {
            float t = 0.f;
            for (int w = 0; w < wpb; w++) t += s[w];
            atomicAdd(lossacc, t);
        }
    }
}

// ---------------- summary + ws = W_dgi @ sigmoid(mean(pos_z)) --------------
__global__ void summary_kernel(const float* __restrict__ colpart,
                               const float* __restrict__ Wdgi,
                               float* __restrict__ wsv, int G, float invN) {
    __shared__ float sm[64];
    __shared__ float s4[4][64];
    int lane = threadIdx.x & 63, w = threadIdx.x >> 6;
    float t = 0.f;
    for (int g = w; g < G; g += 4) t += colpart[(size_t)g * 64 + lane];
    s4[w][lane] = t;
    __syncthreads();
    if (w == 0) {
        t = s4[0][lane] + s4[1][lane] + s4[2][lane] + s4[3][lane];
        sm[lane] = 1.f / (1.f + expf(-t * invN));
    }
    __syncthreads();
    if (threadIdx.x < 64) {
        float a = 0.f;
        for (int j = 0; j < 64; j++) a += Wdgi[threadIdx.x * 64 + j] * sm[j];
        wsv[threadIdx.x] = a;
    }
}

// ---------------- pos loss: -log(sigmoid(z . ws) + eps), mean --------------
__global__ void dot_loss_kernel(const float* __restrict__ z, const float* __restrict__ wsv,
                                float* __restrict__ lossacc, int n) {
    int lane = threadIdx.x & 63, wid = threadIdx.x >> 6, wpb = blockDim.x >> 6;
    __shared__ float s[8];
    float wlane = wsv[lane];
    float lsum = 0.f;
    for (int v = blockIdx.x * wpb + wid; v < n; v += gridDim.x * wpb) {
        float p = z[(size_t)v * 64 + lane] * wlane;
        for (int off = 32; off; off >>= 1) p += __shfl_xor(p, off, 64);
        if (lane == 0) lsum += -logf(1.f / (1.f + expf(-p)) + 1e-15f);
    }
    if (lane == 0) s[wid] = lsum;
    __syncthreads();
    if (threadIdx.x == 0) {
        float t = 0.f;
        for (int w = 0; w < wpb; w++) t += s[w];
        atomicAdd(lossacc, t);
    }
}

__global__ void finalize_kernel(const float* __restrict__ lossacc, float* __restrict__ out,
                                float invN) {
    out[0] = (lossacc[0] + lossacc[1]) * invN;
}

// ---------------------------------------------------------------------------
extern "C" void kernel_launch(void* const* d_in, const int* in_sizes, int n_in,
                              void* d_out, int out_size, void* d_ws, size_t ws_size,
                              hipStream_t stream) {
    const float* x    = (const float*)d_in[0];
    const float* W1   = (const float*)d_in[1];
    const float* b1   = (const float*)d_in[2];
    const float* W2   = (const float*)d_in[3];
    const float* b2   = (const float*)d_in[4];
    const float* Wdgi = (const float*)d_in[5];
    const int*   edge = (const int*)d_in[6];
    const int*   perm = (const int*)d_in[7];

    const int N = in_sizes[7];         // perm length = node count
    const int E = in_sizes[6] / 2;
    const int* row = edge;
    const int* col = edge + E;

    char* wsb = (char*)d_ws;
    size_t off = 0;
    auto alloc = [&](size_t bytes) -> void* {
        void* p = wsb + off;
        off = (off + bytes + 255) & ~(size_t)255;
        return p;
    };
    int*   bucket  = (int*)  alloc((size_t)N * CAP * 4);   // 25.6 MB
    int*   cnt     = (int*)  alloc((size_t)N * 4);
    float* dis     = (float*)alloc((size_t)N * 4);
    float* B1      = (float*)alloc((size_t)N * DD * 4);    // 25.6 MB
    float* B2      = (float*)alloc((size_t)N * DD * 4);    // 25.6 MB
    float* B3      = (float*)alloc((size_t)N * DD * 4);    // 25.6 MB
    float* colpart = (float*)alloc((size_t)GG * 64 * 4);
    float* wsv     = (float*)alloc(64 * 4);
    float* lossacc = (float*)alloc(2 * 4);

    hipMemsetAsync(cnt, 0, (size_t)N * 4, stream);
    hipMemsetAsync(lossacc, 0, 8, stream);

    place_kernel<<<(E + 255) / 256, 256, 0, stream>>>(row, col, bucket, cnt, E);
    dis_kernel<<<(N + 255) / 256, 256, 0, stream>>>(cnt, dis, N);

    // ---- positive branch ----
    gemm64<<<(N + 255) / 256, 256, 0, stream>>>(x, W1, B1, nullptr, N);
    conv_kernel<0><<<(N + 3) / 4, 256, 0, stream>>>(B1, bucket, cnt, dis, b1, B2,
                                                    nullptr, nullptr, nullptr, N);
    gemm64<<<(N + 255) / 256, 256, 0, stream>>>(B2, W2, B1, nullptr, N);
    conv_kernel<1><<<GG, 256, 0, stream>>>(B1, bucket, cnt, dis, b2, B3,
                                           nullptr, colpart, nullptr, N);
    summary_kernel<<<1, 256, 0, stream>>>(colpart, Wdgi, wsv, GG, 1.0f / N);
    dot_loss_kernel<<<GG, 256, 0, stream>>>(B3, wsv, lossacc + 0, N);

    // ---- negative branch (z never materialized) ----
    gemm64<<<(N + 255) / 256, 256, 0, stream>>>(x, W1, B1, perm, N);
    conv_kernel<0><<<(N + 3) / 4, 256, 0, stream>>>(B1, bucket, cnt, dis, b1, B2,
                                                    nullptr, nullptr, nullptr, N);
    gemm64<<<(N + 255) / 256, 256, 0, stream>>>(B2, W2, B1, nullptr, N);
    conv_kernel<2><<<GG, 256, 0, stream>>>(B1, bucket, cnt, dis, b2, nullptr,
                                           wsv, nullptr, lossacc + 1, N);

    finalize_kernel<<<1, 1, 0, stream>>>(lossacc, (float*)d_out, 1.0f / N);
}

// Round 3
// 881.753 us; speedup vs baseline: 1.9331x; 1.9331x over previous
//
#include <hip/hip_runtime.h>
#include <hip/hip_bf16.h>
#include <math.h>

#define CAP 64
#define GG 2048   // fixed grid for conv/loss partial reductions

// ---------------- bucket build: incoming-edge lists per node ----------------
__global__ void place_kernel(const int* __restrict__ row, const int* __restrict__ col,
                             int* __restrict__ bucket, int* __restrict__ cnt, int E) {
    int e = blockIdx.x * blockDim.x + threadIdx.x;
    if (e >= E) return;
    int r = row[e], c = col[e];
    int pos = atomicAdd(&cnt[c], 1);
    if (pos < CAP) bucket[(size_t)c * CAP + pos] = r;
}

__global__ void dis_kernel(const int* __restrict__ cnt, float* __restrict__ dis, int n) {
    int v = blockIdx.x * blockDim.x + threadIdx.x;
    if (v >= n) return;
    dis[v] = rsqrtf((float)cnt[v] + 1.0f);   // deg = in-count + self loop
}

// ---- GEMM: out[v,:] = (X[src(v),:] @ W) * dis[v]   (wave per node) --------
// lane = output dim j. W column j lives in 64 VGPRs (loaded once, coalesced).
// x row read as uniform-address float4 broadcasts; one coalesced 256B store.
__global__ __launch_bounds__(256) void gemm_rowbc(
        const float* __restrict__ X, const float* __restrict__ W,
        const float* __restrict__ dis, float* __restrict__ out,
        const int* __restrict__ perm, int n) {
    int lane = threadIdx.x & 63, wid = threadIdx.x >> 6;
    float w[64];
#pragma unroll
    for (int k = 0; k < 64; k++) w[k] = W[k * 64 + lane];
    int wstart  = blockIdx.x * 4 + wid;
    int wstride = gridDim.x * 4;
    for (int v = wstart; v < n; v += wstride) {
        int src = perm ? perm[v] : v;
        const float4* xr = (const float4*)(X + (size_t)src * 64);
        float a0 = 0.f, a1 = 0.f, a2 = 0.f, a3 = 0.f;
#pragma unroll
        for (int q = 0; q < 16; q++) {
            float4 xv = xr[q];
            a0 = fmaf(xv.x, w[4 * q + 0], a0);
            a1 = fmaf(xv.y, w[4 * q + 1], a1);
            a2 = fmaf(xv.z, w[4 * q + 2], a2);
            a3 = fmaf(xv.w, w[4 * q + 3], a3);
        }
        out[(size_t)v * 64 + lane] = ((a0 + a1) + (a2 + a3)) * dis[v];
    }
}

// ---- fused GCN aggregation, pos+neg together (wave per node, lane = dim) --
// inputs are pre-scaled g = h*dis, so: res = dv*(sum_in g[r] + g[v]) + bias
// MODE 0: relu -> outp/outn.  MODE 1: raw -> outp/outn, col-partials from pos.
template <int MODE>
__global__ __launch_bounds__(256) void conv_fused(
        const float* __restrict__ gp, const float* __restrict__ gn,
        const int* __restrict__ bucket, const int* __restrict__ cnt,
        const float* __restrict__ dis, const float* __restrict__ bias,
        float* __restrict__ outp, float* __restrict__ outn,
        float* __restrict__ colpart, int n) {
    int lane = threadIdx.x & 63, wid = threadIdx.x >> 6;
    __shared__ float s[256];
    float colp  = 0.f;
    float blane = bias[lane];
    int wstart  = blockIdx.x * 4 + wid;
    int wstride = gridDim.x * 4;
    for (int v = wstart; v < n; v += wstride) {
        int c = cnt[v];
        if (c > CAP) c = CAP;
        float dv = dis[v];
        size_t vo = (size_t)v * 64 + lane;
        float a0p = gp[vo], a1p = 0.f, a2p = 0.f, a3p = 0.f;   // self-loop in a0
        float a0n = gn[vo], a1n = 0.f, a2n = 0.f, a3n = 0.f;
        const int*  bk  = bucket + (size_t)v * CAP;
        const int4* bk4 = (const int4*)bk;
        int nq = c >> 2;
        for (int q = 0; q < nq; q++) {
            int4 r = bk4[q];
            size_t o0 = (size_t)r.x * 64 + lane;
            size_t o1 = (size_t)r.y * 64 + lane;
            size_t o2 = (size_t)r.z * 64 + lane;
            size_t o3 = (size_t)r.w * 64 + lane;
            float p0 = gp[o0], p1 = gp[o1], p2 = gp[o2], p3 = gp[o3];
            float q0 = gn[o0], q1 = gn[o1], q2 = gn[o2], q3 = gn[o3];
            a0p += p0; a1p += p1; a2p += p2; a3p += p3;
            a0n += q0; a1n += q1; a2n += q2; a3n += q3;
        }
        for (int i = nq << 2; i < c; i++) {
            size_t o = (size_t)bk[i] * 64 + lane;
            a0p += gp[o];
            a0n += gn[o];
        }
        float sp = (a0p + a1p) + (a2p + a3p);
        float sn = (a0n + a1n) + (a2n + a3n);
        float rp = fmaf(dv, sp, blane);
        float rn = fmaf(dv, sn, blane);
        if (MODE == 0) {
            outp[vo] = fmaxf(rp, 0.f);
            outn[vo] = fmaxf(rn, 0.f);
        } else {
            outp[vo] = rp;
            outn[vo] = rn;
            colp += rp;
        }
    }
    if (MODE == 1) {
        s[wid * 64 + lane] = colp;
        __syncthreads();
        if (wid == 0) {
            float t = s[lane] + s[64 + lane] + s[128 + lane] + s[192 + lane];
            colpart[(size_t)blockIdx.x * 64 + lane] = t;
        }
    }
}

// ---------------- summary + ws = W_dgi @ sigmoid(mean(pos_z)) --------------
__global__ void summary_kernel(const float* __restrict__ colpart,
                               const float* __restrict__ Wdgi,
                               float* __restrict__ wsv, int G, float invN) {
    __shared__ float sm[64];
    __shared__ float s4[4][64];
    int lane = threadIdx.x & 63, w = threadIdx.x >> 6;
    float t = 0.f;
    for (int g = w; g < G; g += 4) t += colpart[(size_t)g * 64 + lane];
    s4[w][lane] = t;
    __syncthreads();
    if (w == 0) {
        t = s4[0][lane] + s4[1][lane] + s4[2][lane] + s4[3][lane];
        sm[lane] = 1.f / (1.f + expf(-t * invN));
    }
    __syncthreads();
    if (threadIdx.x < 64) {
        float a = 0.f;
        for (int j = 0; j < 64; j++) a += Wdgi[threadIdx.x * 64 + j] * sm[j];
        wsv[threadIdx.x] = a;
    }
}

// ---- both losses in one pass: pos uses sigmoid(p), neg uses sigmoid(-q) ---
__global__ __launch_bounds__(256) void loss_kernel(
        const float* __restrict__ zp, const float* __restrict__ zn,
        const float* __restrict__ wsv, float* __restrict__ lossacc, int n) {
    int lane = threadIdx.x & 63, wid = threadIdx.x >> 6;
    __shared__ float s[16];
    float wlane = wsv[lane];
    float lp = 0.f, ln = 0.f;
    int wstart  = blockIdx.x * 4 + wid;
    int wstride = gridDim.x * 4;
    for (int v = wstart; v < n; v += wstride) {
        size_t vo = (size_t)v * 64 + lane;
        float p = zp[vo] * wlane;
        float q = zn[vo] * wlane;
        for (int off = 32; off; off >>= 1) {
            p += __shfl_xor(p, off, 64);
            q += __shfl_xor(q, off, 64);
        }
        if (lane == 0) {
            lp += -logf(1.f / (1.f + expf(-p)) + 1e-15f);   // -log(sigmoid(p)+eps)
            ln += -logf(1.f / (1.f + expf( q)) + 1e-15f);   // -log(1-sigmoid(q)+eps)
        }
    }
    if (lane == 0) { s[wid] = lp; s[8 + wid] = ln; }
    __syncthreads();
    if (threadIdx.x == 0) atomicAdd(&lossacc[0], s[0] + s[1] + s[2] + s[3]);
    if (threadIdx.x == 1) atomicAdd(&lossacc[1], s[8] + s[9] + s[10] + s[11]);
}

__global__ void finalize_kernel(const float* __restrict__ lossacc,
                                float* __restrict__ out, float invN) {
    out[0] = (lossacc[0] + lossacc[1]) * invN;
}

// ---------------------------------------------------------------------------
extern "C" void kernel_launch(void* const* d_in, const int* in_sizes, int n_in,
                              void* d_out, int out_size, void* d_ws, size_t ws_size,
                              hipStream_t stream) {
    const float* x    = (const float*)d_in[0];
    const float* W1   = (const float*)d_in[1];
    const float* b1   = (const float*)d_in[2];
    const float* W2   = (const float*)d_in[3];
    const float* b2   = (const float*)d_in[4];
    const float* Wdgi = (const float*)d_in[5];
    const int*   edge = (const int*)d_in[6];
    const int*   perm = (const int*)d_in[7];

    const int N = in_sizes[7];
    const int E = in_sizes[6] / 2;
    const int* row = edge;
    const int* col = edge + E;

    char* wsb = (char*)d_ws;
    size_t off = 0;
    auto alloc = [&](size_t bytes) -> void* {
        void* p = wsb + off;
        off = (off + bytes + 255) & ~(size_t)255;
        return p;
    };
    int*   bucket  = (int*)  alloc((size_t)N * CAP * 4);   // 25.6 MB
    int*   cnt     = (int*)  alloc((size_t)N * 4);
    float* dis     = (float*)alloc((size_t)N * 4);
    float* Ap      = (float*)alloc((size_t)N * 64 * 4);    // 25.6 MB
    float* An      = (float*)alloc((size_t)N * 64 * 4);
    float* Bp      = (float*)alloc((size_t)N * 64 * 4);
    float* Bn      = (float*)alloc((size_t)N * 64 * 4);
    float* colpart = (float*)alloc((size_t)GG * 64 * 4);
    float* wsv     = (float*)alloc(64 * 4);
    float* lossacc = (float*)alloc(2 * 4);

    hipMemsetAsync(cnt, 0, (size_t)N * 4, stream);
    hipMemsetAsync(lossacc, 0, 8, stream);

    place_kernel<<<(E + 255) / 256, 256, 0, stream>>>(row, col, bucket, cnt, E);
    dis_kernel<<<(N + 255) / 256, 256, 0, stream>>>(cnt, dis, N);

    // layer 1 (dis pre-scale fused into GEMM epilogue)
    gemm_rowbc<<<2048, 256, 0, stream>>>(x, W1, dis, Ap, nullptr, N);
    gemm_rowbc<<<2048, 256, 0, stream>>>(x, W1, dis, An, perm, N);
    conv_fused<0><<<GG, 256, 0, stream>>>(Ap, An, bucket, cnt, dis, b1,
                                          Bp, Bn, nullptr, N);
    // layer 2
    gemm_rowbc<<<2048, 256, 0, stream>>>(Bp, W2, dis, Ap, nullptr, N);
    gemm_rowbc<<<2048, 256, 0, stream>>>(Bn, W2, dis, An, nullptr, N);
    conv_fused<1><<<GG, 256, 0, stream>>>(Ap, An, bucket, cnt, dis, b2,
                                          Bp, Bn, colpart, N);

    summary_kernel<<<1, 256, 0, stream>>>(colpart, Wdgi, wsv, GG, 1.0f / N);
    loss_kernel<<<1024, 256, 0, stream>>>(Bp, Bn, wsv, lossacc, N);
    finalize_kernel<<<1, 1, 0, stream>>>(lossacc, (float*)d_out, 1.0f / N);
}

// Round 4
// 590.996 us; speedup vs baseline: 2.8842x; 1.4920x over previous
//
#include <hip/hip_runtime.h>
#include <hip/hip_bf16.h>
#include <math.h>

#define CAP 64
#define GG 2048   // grid for conv kernels (colpart rows)

typedef __hip_bfloat16 bf16;
typedef unsigned int uint;

__device__ __forceinline__ float b2f(bf16 x) { return __bfloat162float(x); }
__device__ __forceinline__ bf16  f2b(float x) { return __float2bfloat16(x); }
__device__ __forceinline__ float lo16(uint u) { return __uint_as_float(u << 16); }
__device__ __forceinline__ float hi16(uint u) { return __uint_as_float(u & 0xFFFF0000u); }

// ---------------- bucket build: incoming-edge lists per node ----------------
__global__ void place_kernel(const int* __restrict__ row, const int* __restrict__ col,
                             int* __restrict__ bucket, int* __restrict__ cnt, int E) {
    int e = blockIdx.x * blockDim.x + threadIdx.x;
    if (e >= E) return;
    int r = row[e], c = col[e];
    int pos = atomicAdd(&cnt[c], 1);
    if (pos < CAP) bucket[(size_t)c * CAP + pos] = r;
}

// ---- layer-1 GEMM, both branches: g = (X[src] @ W1) * dis[v], bf16 out ----
__global__ __launch_bounds__(256) void gemm1_both(
        const float* __restrict__ X, const float* __restrict__ W,
        const int* __restrict__ perm, const int* __restrict__ cnt,
        bf16* __restrict__ outp, bf16* __restrict__ outn, int n) {
    int lane = threadIdx.x & 63, wid = threadIdx.x >> 6;
    float w[64];
#pragma unroll
    for (int k = 0; k < 64; k++) w[k] = W[k * 64 + lane];
    int wstart = blockIdx.x * 4 + wid, wstride = gridDim.x * 4;
    for (int v = wstart; v < n; v += wstride) {
        float dv = rsqrtf((float)cnt[v] + 1.0f);
        const float4* xp = (const float4*)(X + (size_t)v * 64);
        const float4* xn = (const float4*)(X + (size_t)perm[v] * 64);
        float ap0 = 0.f, ap1 = 0.f, ap2 = 0.f, ap3 = 0.f;
        float an0 = 0.f, an1 = 0.f, an2 = 0.f, an3 = 0.f;
#pragma unroll
        for (int q = 0; q < 16; q++) {
            float4 a = xp[q], b = xn[q];
            ap0 = fmaf(a.x, w[4 * q + 0], ap0);
            ap1 = fmaf(a.y, w[4 * q + 1], ap1);
            ap2 = fmaf(a.z, w[4 * q + 2], ap2);
            ap3 = fmaf(a.w, w[4 * q + 3], ap3);
            an0 = fmaf(b.x, w[4 * q + 0], an0);
            an1 = fmaf(b.y, w[4 * q + 1], an1);
            an2 = fmaf(b.z, w[4 * q + 2], an2);
            an3 = fmaf(b.w, w[4 * q + 3], an3);
        }
        size_t vo = (size_t)v * 64 + lane;
        outp[vo] = f2b(((ap0 + ap1) + (ap2 + ap3)) * dv);
        outn[vo] = f2b(((an0 + an1) + (an2 + an3)) * dv);
    }
}

// ---- layer-2 GEMM, both branches, bf16 in/out: g2 = (H[v] @ W2) * dis[v] --
__global__ __launch_bounds__(256) void gemm2_both(
        const bf16* __restrict__ Hp, const bf16* __restrict__ Hn,
        const float* __restrict__ W, const int* __restrict__ cnt,
        bf16* __restrict__ outp, bf16* __restrict__ outn, int n) {
    int lane = threadIdx.x & 63, wid = threadIdx.x >> 6;
    float w[64];
#pragma unroll
    for (int k = 0; k < 64; k++) w[k] = W[k * 64 + lane];
    int wstart = blockIdx.x * 4 + wid, wstride = gridDim.x * 4;
    for (int v = wstart; v < n; v += wstride) {
        float dv = rsqrtf((float)cnt[v] + 1.0f);
        const uint4* hp = (const uint4*)(Hp + (size_t)v * 64);   // 8 x 16B (8 bf16 each)
        const uint4* hn = (const uint4*)(Hn + (size_t)v * 64);
        float ap = 0.f, an = 0.f;
#pragma unroll
        for (int q = 0; q < 8; q++) {
            uint4 a = hp[q], b = hn[q];
            int k0 = 8 * q;
            ap = fmaf(lo16(a.x), w[k0 + 0], ap); an = fmaf(lo16(b.x), w[k0 + 0], an);
            ap = fmaf(hi16(a.x), w[k0 + 1], ap); an = fmaf(hi16(b.x), w[k0 + 1], an);
            ap = fmaf(lo16(a.y), w[k0 + 2], ap); an = fmaf(lo16(b.y), w[k0 + 2], an);
            ap = fmaf(hi16(a.y), w[k0 + 3], ap); an = fmaf(hi16(b.y), w[k0 + 3], an);
            ap = fmaf(lo16(a.z), w[k0 + 4], ap); an = fmaf(lo16(b.z), w[k0 + 4], an);
            ap = fmaf(hi16(a.z), w[k0 + 5], ap); an = fmaf(hi16(b.z), w[k0 + 5], an);
            ap = fmaf(lo16(a.w), w[k0 + 6], ap); an = fmaf(lo16(b.w), w[k0 + 6], an);
            ap = fmaf(hi16(a.w), w[k0 + 7], ap); an = fmaf(hi16(b.w), w[k0 + 7], an);
        }
        size_t vo = (size_t)v * 64 + lane;
        outp[vo] = f2b(ap * dv);
        outn[vo] = f2b(an * dv);
    }
}

// ---- fused GCN aggregation, pos+neg (wave/node, lane=dim), bf16 in/out ----
// g pre-scaled by dis, so: res = dv*(sum_in g[r] + g[v]) + bias
// MODE 0: relu -> outp/outn.  MODE 1: raw -> outp/outn, col-partials from pos.
template <int MODE>
__global__ __launch_bounds__(256) void conv_bf16(
        const bf16* __restrict__ gp, const bf16* __restrict__ gn,
        const int* __restrict__ bucket, const int* __restrict__ cnt,
        const float* __restrict__ bias,
        bf16* __restrict__ outp, bf16* __restrict__ outn,
        float* __restrict__ colpart, int n) {
    int lane = threadIdx.x & 63, wid = threadIdx.x >> 6;
    __shared__ float s[256];
    float colp  = 0.f;
    float blane = bias[lane];
    int wstart = blockIdx.x * 4 + wid, wstride = gridDim.x * 4;
    for (int v = wstart; v < n; v += wstride) {
        int cf = cnt[v];
        int c  = cf > CAP ? CAP : cf;
        float dv = rsqrtf((float)cf + 1.0f);
        size_t vo = (size_t)v * 64 + lane;
        float a0p = b2f(gp[vo]), a1p = 0.f, a2p = 0.f, a3p = 0.f;   // self-loop in a0
        float a0n = b2f(gn[vo]), a1n = 0.f, a2n = 0.f, a3n = 0.f;
        const int*  bk  = bucket + (size_t)v * CAP;
        const int4* bk4 = (const int4*)bk;
        int nq = c >> 2;
        for (int q = 0; q < nq; q++) {
            int4 r = bk4[q];
            size_t o0 = (size_t)r.x * 64 + lane;
            size_t o1 = (size_t)r.y * 64 + lane;
            size_t o2 = (size_t)r.z * 64 + lane;
            size_t o3 = (size_t)r.w * 64 + lane;
            float p0 = b2f(gp[o0]), p1 = b2f(gp[o1]), p2 = b2f(gp[o2]), p3 = b2f(gp[o3]);
            float q0 = b2f(gn[o0]), q1 = b2f(gn[o1]), q2 = b2f(gn[o2]), q3 = b2f(gn[o3]);
            a0p += p0; a1p += p1; a2p += p2; a3p += p3;
            a0n += q0; a1n += q1; a2n += q2; a3n += q3;
        }
        for (int i = nq << 2; i < c; i++) {
            size_t o = (size_t)bk[i] * 64 + lane;
            a0p += b2f(gp[o]);
            a0n += b2f(gn[o]);
        }
        float sp = (a0p + a1p) + (a2p + a3p);
        float sn = (a0n + a1n) + (a2n + a3n);
        float rp = fmaf(dv, sp, blane);
        float rn = fmaf(dv, sn, blane);
        if (MODE == 0) {
            outp[vo] = f2b(fmaxf(rp, 0.f));
            outn[vo] = f2b(fmaxf(rn, 0.f));
        } else {
            outp[vo] = f2b(rp);
            outn[vo] = f2b(rn);
            colp += rp;           // f32 partial (pre-rounding) for summary
        }
    }
    if (MODE == 1) {
        s[wid * 64 + lane] = colp;
        __syncthreads();
        if (wid == 0) {
            float t = s[lane] + s[64 + lane] + s[128 + lane] + s[192 + lane];
            colpart[(size_t)blockIdx.x * 64 + lane] = t;
        }
    }
}

// ---------------- summary + ws = W_dgi @ sigmoid(mean(pos_z)) --------------
__global__ void summary_kernel(const float* __restrict__ colpart,
                               const float* __restrict__ Wdgi,
                               float* __restrict__ wsv, int G, float invN) {
    __shared__ float sm[64];
    __shared__ float s4[4][64];
    int lane = threadIdx.x & 63, w = threadIdx.x >> 6;
    float t = 0.f;
    for (int g = w; g < G; g += 4) t += colpart[(size_t)g * 64 + lane];
    s4[w][lane] = t;
    __syncthreads();
    if (w == 0) {
        t = s4[0][lane] + s4[1][lane] + s4[2][lane] + s4[3][lane];
        sm[lane] = 1.f / (1.f + expf(-t * invN));
    }
    __syncthreads();
    if (threadIdx.x < 64) {
        float a = 0.f;
        for (int j = 0; j < 64; j++) a += Wdgi[threadIdx.x * 64 + j] * sm[j];
        wsv[threadIdx.x] = a;
    }
}

// ---- both losses in one pass (bf16 z) -------------------------------------
__global__ __launch_bounds__(256) void loss_kernel(
        const bf16* __restrict__ zp, const bf16* __restrict__ zn,
        const float* __restrict__ wsv, float* __restrict__ lossacc, int n) {
    int lane = threadIdx.x & 63, wid = threadIdx.x >> 6;
    __shared__ float s[16];
    float wlane = wsv[lane];
    float lp = 0.f, ln = 0.f;
    int wstart = blockIdx.x * 4 + wid, wstride = gridDim.x * 4;
    for (int v = wstart; v < n; v += wstride) {
        size_t vo = (size_t)v * 64 + lane;
        float p = b2f(zp[vo]) * wlane;
        float q = b2f(zn[vo]) * wlane;
        for (int off = 32; off; off >>= 1) {
            p += __shfl_xor(p, off, 64);
            q += __shfl_xor(q, off, 64);
        }
        if (lane == 0) {
            lp += -logf(1.f / (1.f + expf(-p)) + 1e-15f);   // -log(sigmoid(p)+eps)
            ln += -logf(1.f / (1.f + expf( q)) + 1e-15f);   // -log(1-sigmoid(q)+eps)
        }
    }
    if (lane == 0) { s[wid] = lp; s[8 + wid] = ln; }
    __syncthreads();
    if (threadIdx.x == 0) atomicAdd(&lossacc[0], s[0] + s[1] + s[2] + s[3]);
    if (threadIdx.x == 1) atomicAdd(&lossacc[1], s[8] + s[9] + s[10] + s[11]);
}

__global__ void finalize_kernel(const float* __restrict__ lossacc,
                                float* __restrict__ out, float invN) {
    out[0] = (lossacc[0] + lossacc[1]) * invN;
}

// ---------------------------------------------------------------------------
extern "C" void kernel_launch(void* const* d_in, const int* in_sizes, int n_in,
                              void* d_out, int out_size, void* d_ws, size_t ws_size,
                              hipStream_t stream) {
    const float* x    = (const float*)d_in[0];
    const float* W1   = (const float*)d_in[1];
    const float* b1   = (const float*)d_in[2];
    const float* W2   = (const float*)d_in[3];
    const float* b2   = (const float*)d_in[4];
    const float* Wdgi = (const float*)d_in[5];
    const int*   edge = (const int*)d_in[6];
    const int*   perm = (const int*)d_in[7];

    const int N = in_sizes[7];
    const int E = in_sizes[6] / 2;
    const int* row = edge;
    const int* col = edge + E;

    char* wsb = (char*)d_ws;
    size_t off = 0;
    auto alloc = [&](size_t bytes) -> void* {
        void* p = wsb + off;
        off = (off + bytes + 255) & ~(size_t)255;
        return p;
    };
    int*   bucket  = (int*)  alloc((size_t)N * CAP * 4);   // 25.6 MB
    int*   cnt     = (int*)  alloc((size_t)N * 4);
    bf16*  Gp      = (bf16*) alloc((size_t)N * 64 * 2);    // 12.8 MB each
    bf16*  Gn      = (bf16*) alloc((size_t)N * 64 * 2);
    bf16*  Hp      = (bf16*) alloc((size_t)N * 64 * 2);
    bf16*  Hn      = (bf16*) alloc((size_t)N * 64 * 2);
    float* colpart = (float*)alloc((size_t)GG * 64 * 4);
    float* wsv     = (float*)alloc(64 * 4);
    float* lossacc = (float*)alloc(2 * 4);

    hipMemsetAsync(cnt, 0, (size_t)N * 4, stream);
    hipMemsetAsync(lossacc, 0, 8, stream);

    place_kernel<<<(E + 255) / 256, 256, 0, stream>>>(row, col, bucket, cnt, E);

    // layer 1: G = (X @ W1) * dis  (both branches), then aggregate+relu -> H
    gemm1_both<<<1024, 256, 0, stream>>>(x, W1, perm, cnt, Gp, Gn, N);
    conv_bf16<0><<<GG, 256, 0, stream>>>(Gp, Gn, bucket, cnt, b1, Hp, Hn, nullptr, N);
    // layer 2: G = (H @ W2) * dis, then aggregate -> z (in Hp/Hn) + colpart
    gemm2_both<<<1024, 256, 0, stream>>>(Hp, Hn, W2, cnt, Gp, Gn, N);
    conv_bf16<1><<<GG, 256, 0, stream>>>(Gp, Gn, bucket, cnt, b2, Hp, Hn, colpart, N);

    summary_kernel<<<1, 256, 0, stream>>>(colpart, Wdgi, wsv, GG, 1.0f / N);
    loss_kernel<<<1024, 256, 0, stream>>>(Hp, Hn, wsv, lossacc, N);
    finalize_kernel<<<1, 1, 0, stream>>>(lossacc, (float*)d_out, 1.0f / N);
}

// Round 5
// 583.406 us; speedup vs baseline: 2.9217x; 1.0130x over previous
//
#include <hip/hip_runtime.h>
#include <hip/hip_bf16.h>
#include <math.h>

#define CAP 64
#define GG 2048   // grid for conv kernels (colpart rows)

typedef __hip_bfloat16 bf16;
typedef unsigned int uint;

__device__ __forceinline__ float b2f(bf16 x) { return __bfloat162float(x); }
__device__ __forceinline__ bf16  f2b(float x) { return __float2bfloat16(x); }
__device__ __forceinline__ float lo16(uint u) { return __uint_as_float(u << 16); }
__device__ __forceinline__ float hi16(uint u) { return __uint_as_float(u & 0xFFFF0000u); }

// ---- bucket build, XCD-affinity grouped: group g = blockIdx&7 owns a col
// range; all its blocks land on one XCD (round-robin heuristic) so bucket
// lines are written from a single L2 and write-merge before HBM writeback.
__global__ __launch_bounds__(256) void place_grouped(
        const int* __restrict__ row, const int* __restrict__ col,
        int* __restrict__ bucket, int* __restrict__ cnt, int E, int bound) {
    int g    = blockIdx.x & 7;
    int kb   = blockIdx.x >> 3;
    int K    = gridDim.x >> 3;
    int lo   = g * bound, hi = lo + bound;
    int tid  = kb * blockDim.x + threadIdx.x;
    int nthr = K * blockDim.x;
    int E4   = E >> 2;
    const int4* col4 = (const int4*)col;
    for (int i = tid; i < E4; i += nthr) {
        int4 c4 = c4 = col4[i];
        int e0 = i << 2;
        {
            int c = c4.x;
            if (c >= lo && c < hi) {
                int pos = atomicAdd(&cnt[c], 1);
                if (pos < CAP) bucket[(size_t)c * CAP + pos] = row[e0];
            }
        }
        {
            int c = c4.y;
            if (c >= lo && c < hi) {
                int pos = atomicAdd(&cnt[c], 1);
                if (pos < CAP) bucket[(size_t)c * CAP + pos] = row[e0 + 1];
            }
        }
        {
            int c = c4.z;
            if (c >= lo && c < hi) {
                int pos = atomicAdd(&cnt[c], 1);
                if (pos < CAP) bucket[(size_t)c * CAP + pos] = row[e0 + 2];
            }
        }
        {
            int c = c4.w;
            if (c >= lo && c < hi) {
                int pos = atomicAdd(&cnt[c], 1);
                if (pos < CAP) bucket[(size_t)c * CAP + pos] = row[e0 + 3];
            }
        }
    }
    for (int e = (E4 << 2) + tid; e < E; e += nthr) {
        int c = col[e];
        if (c >= lo && c < hi) {
            int pos = atomicAdd(&cnt[c], 1);
            if (pos < CAP) bucket[(size_t)c * CAP + pos] = row[e];
        }
    }
}

// ---- layer-1 GEMM, both branches: g = (X[src] @ W1) * dis[v], bf16 out ----
__global__ __launch_bounds__(256) void gemm1_both(
        const float* __restrict__ X, const float* __restrict__ W,
        const int* __restrict__ perm, const int* __restrict__ cnt,
        bf16* __restrict__ outp, bf16* __restrict__ outn, int n) {
    int lane = threadIdx.x & 63, wid = threadIdx.x >> 6;
    float w[64];
#pragma unroll
    for (int k = 0; k < 64; k++) w[k] = W[k * 64 + lane];
    int wstart = blockIdx.x * 4 + wid, wstride = gridDim.x * 4;
    for (int v = wstart; v < n; v += wstride) {
        float dv = rsqrtf((float)cnt[v] + 1.0f);
        const float4* xp = (const float4*)(X + (size_t)v * 64);
        const float4* xn = (const float4*)(X + (size_t)perm[v] * 64);
        float ap0 = 0.f, ap1 = 0.f, ap2 = 0.f, ap3 = 0.f;
        float an0 = 0.f, an1 = 0.f, an2 = 0.f, an3 = 0.f;
#pragma unroll
        for (int q = 0; q < 16; q++) {
            float4 a = xp[q], b = xn[q];
            ap0 = fmaf(a.x, w[4 * q + 0], ap0);
            ap1 = fmaf(a.y, w[4 * q + 1], ap1);
            ap2 = fmaf(a.z, w[4 * q + 2], ap2);
            ap3 = fmaf(a.w, w[4 * q + 3], ap3);
            an0 = fmaf(b.x, w[4 * q + 0], an0);
            an1 = fmaf(b.y, w[4 * q + 1], an1);
            an2 = fmaf(b.z, w[4 * q + 2], an2);
            an3 = fmaf(b.w, w[4 * q + 3], an3);
        }
        size_t vo = (size_t)v * 64 + lane;
        outp[vo] = f2b(((ap0 + ap1) + (ap2 + ap3)) * dv);
        outn[vo] = f2b(((an0 + an1) + (an2 + an3)) * dv);
    }
}

// ---- layer-2 GEMM, both branches, bf16 in/out: g2 = (H[v] @ W2) * dis[v] --
__global__ __launch_bounds__(256) void gemm2_both(
        const bf16* __restrict__ Hp, const bf16* __restrict__ Hn,
        const float* __restrict__ W, const int* __restrict__ cnt,
        bf16* __restrict__ outp, bf16* __restrict__ outn, int n) {
    int lane = threadIdx.x & 63, wid = threadIdx.x >> 6;
    float w[64];
#pragma unroll
    for (int k = 0; k < 64; k++) w[k] = W[k * 64 + lane];
    int wstart = blockIdx.x * 4 + wid, wstride = gridDim.x * 4;
    for (int v = wstart; v < n; v += wstride) {
        float dv = rsqrtf((float)cnt[v] + 1.0f);
        const uint4* hp = (const uint4*)(Hp + (size_t)v * 64);
        const uint4* hn = (const uint4*)(Hn + (size_t)v * 64);
        float ap = 0.f, an = 0.f;
#pragma unroll
        for (int q = 0; q < 8; q++) {
            uint4 a = hp[q], b = hn[q];
            int k0 = 8 * q;
            ap = fmaf(lo16(a.x), w[k0 + 0], ap); an = fmaf(lo16(b.x), w[k0 + 0], an);
            ap = fmaf(hi16(a.x), w[k0 + 1], ap); an = fmaf(hi16(b.x), w[k0 + 1], an);
            ap = fmaf(lo16(a.y), w[k0 + 2], ap); an = fmaf(lo16(b.y), w[k0 + 2], an);
            ap = fmaf(hi16(a.y), w[k0 + 3], ap); an = fmaf(hi16(b.y), w[k0 + 3], an);
            ap = fmaf(lo16(a.z), w[k0 + 4], ap); an = fmaf(lo16(b.z), w[k0 + 4], an);
            ap = fmaf(hi16(a.z), w[k0 + 5], ap); an = fmaf(hi16(b.z), w[k0 + 5], an);
            ap = fmaf(lo16(a.w), w[k0 + 6], ap); an = fmaf(lo16(b.w), w[k0 + 6], an);
            ap = fmaf(hi16(a.w), w[k0 + 7], ap); an = fmaf(hi16(b.w), w[k0 + 7], an);
        }
        size_t vo = (size_t)v * 64 + lane;
        outp[vo] = f2b(ap * dv);
        outn[vo] = f2b(an * dv);
    }
}

// ---- fused GCN aggregation, pos+neg (wave/node, lane=dim), bf16 in/out ----
// g pre-scaled by dis, so: res = dv*(sum_in g[r] + g[v]) + bias
// MODE 0: relu -> outp/outn.  MODE 1: raw -> outp/outn, col-partials from pos.
template <int MODE>
__global__ __launch_bounds__(256) void conv_bf16(
        const bf16* __restrict__ gp, const bf16* __restrict__ gn,
        const int* __restrict__ bucket, const int* __restrict__ cnt,
        const float* __restrict__ bias,
        bf16* __restrict__ outp, bf16* __restrict__ outn,
        float* __restrict__ colpart, int n) {
    int lane = threadIdx.x & 63, wid = threadIdx.x >> 6;
    __shared__ float s[256];
    float colp  = 0.f;
    float blane = bias[lane];
    int wstart = blockIdx.x * 4 + wid, wstride = gridDim.x * 4;
    for (int v = wstart; v < n; v += wstride) {
        int cf = cnt[v];
        int c  = cf > CAP ? CAP : cf;
        float dv = rsqrtf((float)cf + 1.0f);
        size_t vo = (size_t)v * 64 + lane;
        float a0p = b2f(gp[vo]), a1p = 0.f, a2p = 0.f, a3p = 0.f;   // self-loop in a0
        float a0n = b2f(gn[vo]), a1n = 0.f, a2n = 0.f, a3n = 0.f;
        const int*  bk  = bucket + (size_t)v * CAP;
        const int4* bk4 = (const int4*)bk;
        // 8-wide chunks: 16 independent row gathers in flight
        int nq8 = c >> 3;
        for (int q = 0; q < nq8; q++) {
            int4 ra = bk4[2 * q], rb = bk4[2 * q + 1];
            size_t o0 = (size_t)ra.x * 64 + lane;
            size_t o1 = (size_t)ra.y * 64 + lane;
            size_t o2 = (size_t)ra.z * 64 + lane;
            size_t o3 = (size_t)ra.w * 64 + lane;
            size_t o4 = (size_t)rb.x * 64 + lane;
            size_t o5 = (size_t)rb.y * 64 + lane;
            size_t o6 = (size_t)rb.z * 64 + lane;
            size_t o7 = (size_t)rb.w * 64 + lane;
            float p0 = b2f(gp[o0]), p1 = b2f(gp[o1]), p2 = b2f(gp[o2]), p3 = b2f(gp[o3]);
            float p4 = b2f(gp[o4]), p5 = b2f(gp[o5]), p6 = b2f(gp[o6]), p7 = b2f(gp[o7]);
            float q0 = b2f(gn[o0]), q1 = b2f(gn[o1]), q2 = b2f(gn[o2]), q3 = b2f(gn[o3]);
            float q4 = b2f(gn[o4]), q5 = b2f(gn[o5]), q6 = b2f(gn[o6]), q7 = b2f(gn[o7]);
            a0p += p0 + p4; a1p += p1 + p5; a2p += p2 + p6; a3p += p3 + p7;
            a0n += q0 + q4; a1n += q1 + q5; a2n += q2 + q6; a3n += q3 + q7;
        }
        int i = nq8 << 3;
        if (c - i >= 4) {
            int4 r = bk4[i >> 2];
            size_t o0 = (size_t)r.x * 64 + lane;
            size_t o1 = (size_t)r.y * 64 + lane;
            size_t o2 = (size_t)r.z * 64 + lane;
            size_t o3 = (size_t)r.w * 64 + lane;
            a0p += b2f(gp[o0]); a1p += b2f(gp[o1]); a2p += b2f(gp[o2]); a3p += b2f(gp[o3]);
            a0n += b2f(gn[o0]); a1n += b2f(gn[o1]); a2n += b2f(gn[o2]); a3n += b2f(gn[o3]);
            i += 4;
        }
        for (; i < c; i++) {
            size_t o = (size_t)bk[i] * 64 + lane;
            a0p += b2f(gp[o]);
            a0n += b2f(gn[o]);
        }
        float sp = (a0p + a1p) + (a2p + a3p);
        float sn = (a0n + a1n) + (a2n + a3n);
        float rp = fmaf(dv, sp, blane);
        float rn = fmaf(dv, sn, blane);
        if (MODE == 0) {
            outp[vo] = f2b(fmaxf(rp, 0.f));
            outn[vo] = f2b(fmaxf(rn, 0.f));
        } else {
            outp[vo] = f2b(rp);
            outn[vo] = f2b(rn);
            colp += rp;           // f32 partial (pre-rounding) for summary
        }
    }
    if (MODE == 1) {
        s[wid * 64 + lane] = colp;
        __syncthreads();
        if (wid == 0) {
            float t = s[lane] + s[64 + lane] + s[128 + lane] + s[192 + lane];
            colpart[(size_t)blockIdx.x * 64 + lane] = t;
        }
    }
}

// ---------------- summary + ws = W_dgi @ sigmoid(mean(pos_z)) --------------
__global__ void summary_kernel(const float* __restrict__ colpart,
                               const float* __restrict__ Wdgi,
                               float* __restrict__ wsv, int G, float invN) {
    __shared__ float sm[64];
    __shared__ float s4[4][64];
    int lane = threadIdx.x & 63, w = threadIdx.x >> 6;
    float t = 0.f;
    for (int g = w; g < G; g += 4) t += colpart[(size_t)g * 64 + lane];
    s4[w][lane] = t;
    __syncthreads();
    if (w == 0) {
        t = s4[0][lane] + s4[1][lane] + s4[2][lane] + s4[3][lane];
        sm[lane] = 1.f / (1.f + expf(-t * invN));
    }
    __syncthreads();
    if (threadIdx.x < 64) {
        float a = 0.f;
        for (int j = 0; j < 64; j++) a += Wdgi[threadIdx.x * 64 + j] * sm[j];
        wsv[threadIdx.x] = a;
    }
}

// ---- both losses in one pass (bf16 z) -------------------------------------
__global__ __launch_bounds__(256) void loss_kernel(
        const bf16* __restrict__ zp, const bf16* __restrict__ zn,
        const float* __restrict__ wsv, float* __restrict__ lossacc, int n) {
    int lane = threadIdx.x & 63, wid = threadIdx.x >> 6;
    __shared__ float s[16];
    float wlane = wsv[lane];
    float lp = 0.f, ln = 0.f;
    int wstart = blockIdx.x * 4 + wid, wstride = gridDim.x * 4;
    for (int v = wstart; v < n; v += wstride) {
        size_t vo = (size_t)v * 64 + lane;
        float p = b2f(zp[vo]) * wlane;
        float q = b2f(zn[vo]) * wlane;
        for (int off = 32; off; off >>= 1) {
            p += __shfl_xor(p, off, 64);
            q += __shfl_xor(q, off, 64);
        }
        if (lane == 0) {
            lp += -logf(1.f / (1.f + expf(-p)) + 1e-15f);   // -log(sigmoid(p)+eps)
            ln += -logf(1.f / (1.f + expf( q)) + 1e-15f);   // -log(1-sigmoid(q)+eps)
        }
    }
    if (lane == 0) { s[wid] = lp; s[8 + wid] = ln; }
    __syncthreads();
    if (threadIdx.x == 0) atomicAdd(&lossacc[0], s[0] + s[1] + s[2] + s[3]);
    if (threadIdx.x == 1) atomicAdd(&lossacc[1], s[8] + s[9] + s[10] + s[11]);
}

__global__ void finalize_kernel(const float* __restrict__ lossacc,
                                float* __restrict__ out, float invN) {
    out[0] = (lossacc[0] + lossacc[1]) * invN;
}

// ---------------------------------------------------------------------------
extern "C" void kernel_launch(void* const* d_in, const int* in_sizes, int n_in,
                              void* d_out, int out_size, void* d_ws, size_t ws_size,
                              hipStream_t stream) {
    const float* x    = (const float*)d_in[0];
    const float* W1   = (const float*)d_in[1];
    const float* b1   = (const float*)d_in[2];
    const float* W2   = (const float*)d_in[3];
    const float* b2   = (const float*)d_in[4];
    const float* Wdgi = (const float*)d_in[5];
    const int*   edge = (const int*)d_in[6];
    const int*   perm = (const int*)d_in[7];

    const int N = in_sizes[7];
    const int E = in_sizes[6] / 2;
    const int* row = edge;
    const int* col = edge + E;

    char* wsb = (char*)d_ws;
    size_t off = 0;
    auto alloc = [&](size_t bytes) -> void* {
        void* p = wsb + off;
        off = (off + bytes + 255) & ~(size_t)255;
        return p;
    };
    int*   bucket  = (int*)  alloc((size_t)N * CAP * 4);   // 25.6 MB
    int*   cnt     = (int*)  alloc((size_t)N * 4);
    bf16*  Gp      = (bf16*) alloc((size_t)N * 64 * 2);    // 12.8 MB each
    bf16*  Gn      = (bf16*) alloc((size_t)N * 64 * 2);
    bf16*  Hp      = (bf16*) alloc((size_t)N * 64 * 2);
    bf16*  Hn      = (bf16*) alloc((size_t)N * 64 * 2);
    float* colpart = (float*)alloc((size_t)GG * 64 * 4);
    float* wsv     = (float*)alloc(64 * 4);
    float* lossacc = (float*)alloc(2 * 4);

    hipMemsetAsync(cnt, 0, (size_t)N * 4, stream);
    hipMemsetAsync(lossacc, 0, 8, stream);

    const int bound = (N + 7) / 8;   // col-range per XCD group
    place_grouped<<<1024, 256, 0, stream>>>(row, col, bucket, cnt, E, bound);

    // layer 1: G = (X @ W1) * dis  (both branches), then aggregate+relu -> H
    gemm1_both<<<1024, 256, 0, stream>>>(x, W1, perm, cnt, Gp, Gn, N);
    conv_bf16<0><<<GG, 256, 0, stream>>>(Gp, Gn, bucket, cnt, b1, Hp, Hn, nullptr, N);
    // layer 2: G = (H @ W2) * dis, then aggregate -> z (in Hp/Hn) + colpart
    gemm2_both<<<1024, 256, 0, stream>>>(Hp, Hn, W2, cnt, Gp, Gn, N);
    conv_bf16<1><<<GG, 256, 0, stream>>>(Gp, Gn, bucket, cnt, b2, Hp, Hn, colpart, N);

    summary_kernel<<<1, 256, 0, stream>>>(colpart, Wdgi, wsv, GG, 1.0f / N);
    loss_kernel<<<1024, 256, 0, stream>>>(Hp, Hn, wsv, lossacc, N);
    finalize_kernel<<<1, 1, 0, stream>>>(lossacc, (float*)d_out, 1.0f / N);
}

// Round 6
// 432.925 us; speedup vs baseline: 3.9373x; 1.3476x over previous
//
#include <hip/hip_runtime.h>
#include <hip/hip_bf16.h>
#include <math.h>

#define CAP 64
#define GG 2048     // conv grid (colpart rows)
#define RB 32       // colpart rows per stage-A block (GG/RB = 64 stage-A blocks)

typedef __hip_bfloat16 bf16;
typedef unsigned int uint;
typedef unsigned short ushort;

__device__ __forceinline__ bf16  f2b(float x) { return __float2bfloat16(x); }
// packed pos/neg: low 16 bits = bf16(pos), high 16 bits = bf16(neg)
__device__ __forceinline__ float posf(uint u) { return __uint_as_float(u << 16); }
__device__ __forceinline__ float negf(uint u) { return __uint_as_float(u & 0xFFFF0000u); }
__device__ __forceinline__ uint  packbf(float p, float n) {
    bf16 bp = f2b(p), bn = f2b(n);
    ushort up = *reinterpret_cast<ushort*>(&bp);
    ushort un = *reinterpret_cast<ushort*>(&bn);
    return (uint)up | ((uint)un << 16);
}

// ---- bucket build, XCD-affinity grouped (see R4): group g=blockIdx&7 owns
// a col range so bucket lines are written from one XCD's L2 and write-merge.
__global__ __launch_bounds__(256) void place_grouped(
        const int* __restrict__ row, const int* __restrict__ col,
        int* __restrict__ bucket, int* __restrict__ cnt, int E, int bound) {
    int g    = blockIdx.x & 7;
    int kb   = blockIdx.x >> 3;
    int K    = gridDim.x >> 3;
    int lo   = g * bound, hi = lo + bound;
    int tid  = kb * blockDim.x + threadIdx.x;
    int nthr = K * blockDim.x;
    int E4   = E >> 2;
    const int4* col4 = (const int4*)col;
    for (int i = tid; i < E4; i += nthr) {
        int4 c4 = col4[i];
        int e0 = i << 2;
        if (c4.x >= lo && c4.x < hi) {
            int pos = atomicAdd(&cnt[c4.x], 1);
            if (pos < CAP) bucket[(size_t)c4.x * CAP + pos] = row[e0];
        }
        if (c4.y >= lo && c4.y < hi) {
            int pos = atomicAdd(&cnt[c4.y], 1);
            if (pos < CAP) bucket[(size_t)c4.y * CAP + pos] = row[e0 + 1];
        }
        if (c4.z >= lo && c4.z < hi) {
            int pos = atomicAdd(&cnt[c4.z], 1);
            if (pos < CAP) bucket[(size_t)c4.z * CAP + pos] = row[e0 + 2];
        }
        if (c4.w >= lo && c4.w < hi) {
            int pos = atomicAdd(&cnt[c4.w], 1);
            if (pos < CAP) bucket[(size_t)c4.w * CAP + pos] = row[e0 + 3];
        }
    }
    for (int e = (E4 << 2) + tid; e < E; e += nthr) {
        int c = col[e];
        if (c >= lo && c < hi) {
            int pos = atomicAdd(&cnt[c], 1);
            if (pos < CAP) bucket[(size_t)c * CAP + pos] = row[e];
        }
    }
}

// ---- layer-1 GEMM: packed out = {(X[v]@W1)*dv, (X[perm v]@W1)*dv} ---------
__global__ __launch_bounds__(256) void gemm1_both(
        const float* __restrict__ X, const float* __restrict__ W,
        const int* __restrict__ perm, const int* __restrict__ cnt,
        uint* __restrict__ out, int n) {
    int lane = threadIdx.x & 63, wid = threadIdx.x >> 6;
    float w[64];
#pragma unroll
    for (int k = 0; k < 64; k++) w[k] = W[k * 64 + lane];
    int wstart = blockIdx.x * 4 + wid, wstride = gridDim.x * 4;
    for (int v = wstart; v < n; v += wstride) {
        float dv = rsqrtf((float)cnt[v] + 1.0f);
        const float4* xp = (const float4*)(X + (size_t)v * 64);
        const float4* xn = (const float4*)(X + (size_t)perm[v] * 64);
        float ap0 = 0.f, ap1 = 0.f, ap2 = 0.f, ap3 = 0.f;
        float an0 = 0.f, an1 = 0.f, an2 = 0.f, an3 = 0.f;
#pragma unroll
        for (int q = 0; q < 16; q++) {
            float4 a = xp[q], b = xn[q];
            ap0 = fmaf(a.x, w[4 * q + 0], ap0);
            ap1 = fmaf(a.y, w[4 * q + 1], ap1);
            ap2 = fmaf(a.z, w[4 * q + 2], ap2);
            ap3 = fmaf(a.w, w[4 * q + 3], ap3);
            an0 = fmaf(b.x, w[4 * q + 0], an0);
            an1 = fmaf(b.y, w[4 * q + 1], an1);
            an2 = fmaf(b.z, w[4 * q + 2], an2);
            an3 = fmaf(b.w, w[4 * q + 3], an3);
        }
        out[(size_t)v * 64 + lane] =
            packbf(((ap0 + ap1) + (ap2 + ap3)) * dv, ((an0 + an1) + (an2 + an3)) * dv);
    }
}

// ---- layer-2 GEMM, packed in/out: g2 = (H[v] @ W2) * dis[v] ---------------
__global__ __launch_bounds__(256) void gemm2_both(
        const uint* __restrict__ H, const float* __restrict__ W,
        const int* __restrict__ cnt, uint* __restrict__ out, int n) {
    int lane = threadIdx.x & 63, wid = threadIdx.x >> 6;
    float w[64];
#pragma unroll
    for (int k = 0; k < 64; k++) w[k] = W[k * 64 + lane];
    int wstart = blockIdx.x * 4 + wid, wstride = gridDim.x * 4;
    for (int v = wstart; v < n; v += wstride) {
        float dv = rsqrtf((float)cnt[v] + 1.0f);
        const uint4* h = (const uint4*)(H + (size_t)v * 64);
        float ap = 0.f, an = 0.f;
#pragma unroll
        for (int q = 0; q < 16; q++) {
            uint4 a = h[q];
            int k0 = 4 * q;
            ap = fmaf(posf(a.x), w[k0 + 0], ap); an = fmaf(negf(a.x), w[k0 + 0], an);
            ap = fmaf(posf(a.y), w[k0 + 1], ap); an = fmaf(negf(a.y), w[k0 + 1], an);
            ap = fmaf(posf(a.z), w[k0 + 2], ap); an = fmaf(negf(a.z), w[k0 + 2], an);
            ap = fmaf(posf(a.w), w[k0 + 3], ap); an = fmaf(negf(a.w), w[k0 + 3], an);
        }
        out[(size_t)v * 64 + lane] = packbf(ap * dv, an * dv);
    }
}

// ---- fused GCN aggregation, packed pos/neg (wave/node, lane=dim) ----------
// g pre-scaled by dis:  res = dv*(sum_in g[r] + g[v]) + bias
// MODE 0: relu -> out.  MODE 1: raw -> out, pos col-partials -> colpart.
template <int MODE>
__global__ __launch_bounds__(256) void conv_packed(
        const uint* __restrict__ g, const int* __restrict__ bucket,
        const int* __restrict__ cnt, const float* __restrict__ bias,
        uint* __restrict__ out, float* __restrict__ colpart, int n) {
    int lane = threadIdx.x & 63, wid = threadIdx.x >> 6;
    __shared__ float s[256];
    float colp  = 0.f;
    float blane = bias[lane];
    int wstart = blockIdx.x * 4 + wid, wstride = gridDim.x * 4;
    for (int v = wstart; v < n; v += wstride) {
        int cf = cnt[v];
        int c  = cf > CAP ? CAP : cf;
        float dv = rsqrtf((float)cf + 1.0f);
        size_t vo = (size_t)v * 64 + lane;
        uint su = g[vo];
        float a0p = posf(su), a1p = 0.f, a2p = 0.f, a3p = 0.f;   // self in a0
        float a0n = negf(su), a1n = 0.f, a2n = 0.f, a3n = 0.f;
        const int*  bk  = bucket + (size_t)v * CAP;
        const int4* bk4 = (const int4*)bk;
        int nq8 = c >> 3;
        for (int q = 0; q < nq8; q++) {
            int4 ra = bk4[2 * q], rb = bk4[2 * q + 1];
            uint u0 = g[(size_t)ra.x * 64 + lane];
            uint u1 = g[(size_t)ra.y * 64 + lane];
            uint u2 = g[(size_t)ra.z * 64 + lane];
            uint u3 = g[(size_t)ra.w * 64 + lane];
            uint u4 = g[(size_t)rb.x * 64 + lane];
            uint u5 = g[(size_t)rb.y * 64 + lane];
            uint u6 = g[(size_t)rb.z * 64 + lane];
            uint u7 = g[(size_t)rb.w * 64 + lane];
            a0p += posf(u0) + posf(u4); a0n += negf(u0) + negf(u4);
            a1p += posf(u1) + posf(u5); a1n += negf(u1) + negf(u5);
            a2p += posf(u2) + posf(u6); a2n += negf(u2) + negf(u6);
            a3p += posf(u3) + posf(u7); a3n += negf(u3) + negf(u7);
        }
        int i = nq8 << 3;
        if (c - i >= 4) {
            int4 r = bk4[i >> 2];
            uint u0 = g[(size_t)r.x * 64 + lane];
            uint u1 = g[(size_t)r.y * 64 + lane];
            uint u2 = g[(size_t)r.z * 64 + lane];
            uint u3 = g[(size_t)r.w * 64 + lane];
            a0p += posf(u0); a0n += negf(u0);
            a1p += posf(u1); a1n += negf(u1);
            a2p += posf(u2); a2n += negf(u2);
            a3p += posf(u3); a3n += negf(u3);
            i += 4;
        }
        for (; i < c; i++) {
            uint u = g[(size_t)bk[i] * 64 + lane];
            a0p += posf(u);
            a0n += negf(u);
        }
        float sp = (a0p + a1p) + (a2p + a3p);
        float sn = (a0n + a1n) + (a2n + a3n);
        float rp = fmaf(dv, sp, blane);
        float rn = fmaf(dv, sn, blane);
        if (MODE == 0) {
            out[vo] = packbf(fmaxf(rp, 0.f), fmaxf(rn, 0.f));
        } else {
            out[vo] = packbf(rp, rn);
            colp += rp;           // f32 partial (pre-rounding) for summary
        }
    }
    if (MODE == 1) {
        s[wid * 64 + lane] = colp;
        __syncthreads();
        if (wid == 0) {
            float t = s[lane] + s[64 + lane] + s[128 + lane] + s[192 + lane];
            colpart[(size_t)blockIdx.x * 64 + lane] = t;
        }
    }
}

// ---- stage A: sum RB colpart rows per block -> colpart2 (GG/RB rows) ------
__global__ __launch_bounds__(256) void colreduce_kernel(
        const float* __restrict__ colpart, float* __restrict__ colpart2) {
    int lane = threadIdx.x & 63, w = threadIdx.x >> 6;
    __shared__ float s4[4][64];
    float t = 0.f;
    int base = blockIdx.x * RB;
    for (int g = w; g < RB; g += 4) t += colpart[(size_t)(base + g) * 64 + lane];
    s4[w][lane] = t;
    __syncthreads();
    if (w == 0)
        colpart2[(size_t)blockIdx.x * 64 + lane] =
            s4[0][lane] + s4[1][lane] + s4[2][lane] + s4[3][lane];
}

// ---- summary + ws = W_dgi @ sigmoid(mean(pos_z)) --------------------------
__global__ void summary_kernel(const float* __restrict__ colpart,
                               const float* __restrict__ Wdgi,
                               float* __restrict__ wsv, int G, float invN) {
    __shared__ float sm[64];
    __shared__ float s4[4][64];
    int lane = threadIdx.x & 63, w = threadIdx.x >> 6;
    float t = 0.f;
    for (int g = w; g < G; g += 4) t += colpart[(size_t)g * 64 + lane];
    s4[w][lane] = t;
    __syncthreads();
    if (w == 0) {
        t = s4[0][lane] + s4[1][lane] + s4[2][lane] + s4[3][lane];
        sm[lane] = 1.f / (1.f + expf(-t * invN));
    }
    __syncthreads();
    if (threadIdx.x < 64) {
        float a = 0.f;
        for (int j = 0; j < 64; j++) a += Wdgi[threadIdx.x * 64 + j] * sm[j];
        wsv[threadIdx.x] = a;
    }
}

// ---- both losses in one pass (packed z) -----------------------------------
__global__ __launch_bounds__(256) void loss_kernel(
        const uint* __restrict__ z, const float* __restrict__ wsv,
        float* __restrict__ lossacc, int n) {
    int lane = threadIdx.x & 63, wid = threadIdx.x >> 6;
    __shared__ float s[16];
    float wlane = wsv[lane];
    float lp = 0.f, ln = 0.f;
    int wstart = blockIdx.x * 4 + wid, wstride = gridDim.x * 4;
    for (int v = wstart; v < n; v += wstride) {
        uint u = z[(size_t)v * 64 + lane];
        float p = posf(u) * wlane;
        float q = negf(u) * wlane;
        for (int off = 32; off; off >>= 1) {
            p += __shfl_xor(p, off, 64);
            q += __shfl_xor(q, off, 64);
        }
        if (lane == 0) {
            lp += -logf(1.f / (1.f + expf(-p)) + 1e-15f);   // -log(sigmoid(p)+eps)
            ln += -logf(1.f / (1.f + expf( q)) + 1e-15f);   // -log(1-sigmoid(q)+eps)
        }
    }
    if (lane == 0) { s[wid] = lp; s[8 + wid] = ln; }
    __syncthreads();
    if (threadIdx.x == 0) atomicAdd(&lossacc[0], s[0] + s[1] + s[2] + s[3]);
    if (threadIdx.x == 1) atomicAdd(&lossacc[1], s[8] + s[9] + s[10] + s[11]);
}

__global__ void finalize_kernel(const float* __restrict__ lossacc,
                                float* __restrict__ out, float invN) {
    out[0] = (lossacc[0] + lossacc[1]) * invN;
}

// ---------------------------------------------------------------------------
extern "C" void kernel_launch(void* const* d_in, const int* in_sizes, int n_in,
                              void* d_out, int out_size, void* d_ws, size_t ws_size,
                              hipStream_t stream) {
    const float* x    = (const float*)d_in[0];
    const float* W1   = (const float*)d_in[1];
    const float* b1   = (const float*)d_in[2];
    const float* W2   = (const float*)d_in[3];
    const float* b2   = (const float*)d_in[4];
    const float* Wdgi = (const float*)d_in[5];
    const int*   edge = (const int*)d_in[6];
    const int*   perm = (const int*)d_in[7];

    const int N = in_sizes[7];
    const int E = in_sizes[6] / 2;
    const int* row = edge;
    const int* col = edge + E;

    char* wsb = (char*)d_ws;
    size_t off = 0;
    auto alloc = [&](size_t bytes) -> void* {
        void* p = wsb + off;
        off = (off + bytes + 255) & ~(size_t)255;
        return p;
    };
    int*   bucket   = (int*)  alloc((size_t)N * CAP * 4);   // 25.6 MB
    int*   cnt      = (int*)  alloc((size_t)N * 4);
    uint*  G        = (uint*) alloc((size_t)N * 64 * 4);    // packed pos/neg, 25.6 MB
    uint*  H        = (uint*) alloc((size_t)N * 64 * 4);
    float* colpart  = (float*)alloc((size_t)GG * 64 * 4);
    float* colpart2 = (float*)alloc((size_t)(GG / RB) * 64 * 4);
    float* wsv      = (float*)alloc(64 * 4);
    float* lossacc  = (float*)alloc(2 * 4);

    hipMemsetAsync(cnt, 0, (size_t)N * 4, stream);
    hipMemsetAsync(lossacc, 0, 8, stream);

    const int bound = (N + 7) / 8;   // col-range per XCD group
    place_grouped<<<1024, 256, 0, stream>>>(row, col, bucket, cnt, E, bound);

    // layer 1: G = (X @ W1) * dis (both branches packed), aggregate+relu -> H
    gemm1_both<<<1024, 256, 0, stream>>>(x, W1, perm, cnt, G, N);
    conv_packed<0><<<GG, 256, 0, stream>>>(G, bucket, cnt, b1, H, nullptr, N);
    // layer 2: G = (H @ W2) * dis, aggregate -> z (in H) + colpart
    gemm2_both<<<1024, 256, 0, stream>>>(H, W2, cnt, G, N);
    conv_packed<1><<<GG, 256, 0, stream>>>(G, bucket, cnt, b2, H, colpart, N);

    colreduce_kernel<<<GG / RB, 256, 0, stream>>>(colpart, colpart2);
    summary_kernel<<<1, 256, 0, stream>>>(colpart2, Wdgi, wsv, GG / RB, 1.0f / N);
    loss_kernel<<<1024, 256, 0, stream>>>(H, wsv, lossacc, N);
    finalize_kernel<<<1, 1, 0, stream>>>(lossacc, (float*)d_out, 1.0f / N);
}

// Round 7
// 356.749 us; speedup vs baseline: 4.7780x; 1.2135x over previous
//
#include <hip/hip_runtime.h>
#include <hip/hip_bf16.h>
#include <math.h>

#define CAP 64
#define GG 2048     // conv grid (colpart rows)
#define RB 32       // colpart rows per stage-A block (GG/RB = 64 stage-A blocks)

typedef __hip_bfloat16 bf16;
typedef unsigned int uint;
typedef unsigned short ushort;

__device__ __forceinline__ bf16  f2b(float x) { return __float2bfloat16(x); }
// packed pos/neg: low 16 bits = bf16(pos), high 16 bits = bf16(neg)
__device__ __forceinline__ float posf(uint u) { return __uint_as_float(u << 16); }
__device__ __forceinline__ float negf(uint u) { return __uint_as_float(u & 0xFFFF0000u); }
__device__ __forceinline__ uint  packbf(float p, float n) {
    bf16 bp = f2b(p), bn = f2b(n);
    ushort up = *reinterpret_cast<ushort*>(&bp);
    ushort un = *reinterpret_cast<ushort*>(&bn);
    return (uint)up | ((uint)un << 16);
}
__device__ __forceinline__ float rdlane_f(float v, int k) {
    return __uint_as_float(__builtin_amdgcn_readlane(__float_as_uint(v), k));
}

// ---- bucket build, XCD-affinity grouped (see R4): group g=blockIdx&7 owns
// a col range so bucket lines are written from one XCD's L2 and write-merge.
__global__ __launch_bounds__(256) void place_grouped(
        const int* __restrict__ row, const int* __restrict__ col,
        int* __restrict__ bucket, int* __restrict__ cnt, int E, int bound) {
    int g    = blockIdx.x & 7;
    int kb   = blockIdx.x >> 3;
    int K    = gridDim.x >> 3;
    int lo   = g * bound, hi = lo + bound;
    int tid  = kb * blockDim.x + threadIdx.x;
    int nthr = K * blockDim.x;
    int E4   = E >> 2;
    const int4* col4 = (const int4*)col;
    for (int i = tid; i < E4; i += nthr) {
        int4 c4 = col4[i];
        int e0 = i << 2;
        if (c4.x >= lo && c4.x < hi) {
            int pos = atomicAdd(&cnt[c4.x], 1);
            if (pos < CAP) bucket[(size_t)c4.x * CAP + pos] = row[e0];
        }
        if (c4.y >= lo && c4.y < hi) {
            int pos = atomicAdd(&cnt[c4.y], 1);
            if (pos < CAP) bucket[(size_t)c4.y * CAP + pos] = row[e0 + 1];
        }
        if (c4.z >= lo && c4.z < hi) {
            int pos = atomicAdd(&cnt[c4.z], 1);
            if (pos < CAP) bucket[(size_t)c4.z * CAP + pos] = row[e0 + 2];
        }
        if (c4.w >= lo && c4.w < hi) {
            int pos = atomicAdd(&cnt[c4.w], 1);
            if (pos < CAP) bucket[(size_t)c4.w * CAP + pos] = row[e0 + 3];
        }
    }
    for (int e = (E4 << 2) + tid; e < E; e += nthr) {
        int c = col[e];
        if (c >= lo && c < hi) {
            int pos = atomicAdd(&cnt[c], 1);
            if (pos < CAP) bucket[(size_t)c * CAP + pos] = row[e];
        }
    }
}

// ---- layer-1 GEMM: coalesced row load + readlane broadcast ----------------
// wave per node, lane = outdim j. x row loaded once coalesced (1 VGPR/branch),
// broadcast per-k via v_readlane (SGPR operand folds into the FMA).
__global__ __launch_bounds__(256) void gemm1_both(
        const float* __restrict__ X, const float* __restrict__ W,
        const int* __restrict__ perm, const int* __restrict__ cnt,
        uint* __restrict__ out, int n) {
    int lane = threadIdx.x & 63, wid = threadIdx.x >> 6;
    float w[64];
#pragma unroll
    for (int k = 0; k < 64; k++) w[k] = W[k * 64 + lane];
    int wstart = blockIdx.x * 4 + wid, wstride = gridDim.x * 4;
    for (int v = wstart; v < n; v += wstride) {
        float xp = X[(size_t)v * 64 + lane];
        float xn = X[(size_t)perm[v] * 64 + lane];
        float dv = rsqrtf((float)cnt[v] + 1.0f);
        float ap0 = 0.f, ap1 = 0.f, an0 = 0.f, an1 = 0.f;
#pragma unroll
        for (int k = 0; k < 64; k += 2) {
            float xp0 = rdlane_f(xp, k),     xn0 = rdlane_f(xn, k);
            float xp1 = rdlane_f(xp, k + 1), xn1 = rdlane_f(xn, k + 1);
            ap0 = fmaf(xp0, w[k], ap0);     an0 = fmaf(xn0, w[k], an0);
            ap1 = fmaf(xp1, w[k + 1], ap1); an1 = fmaf(xn1, w[k + 1], an1);
        }
        out[(size_t)v * 64 + lane] = packbf((ap0 + ap1) * dv, (an0 + an1) * dv);
    }
}

// ---- layer-2 GEMM, packed in/out: one readlane serves both branches -------
__global__ __launch_bounds__(256) void gemm2_both(
        const uint* __restrict__ H, const float* __restrict__ W,
        const int* __restrict__ cnt, uint* __restrict__ out, int n) {
    int lane = threadIdx.x & 63, wid = threadIdx.x >> 6;
    float w[64];
#pragma unroll
    for (int k = 0; k < 64; k++) w[k] = W[k * 64 + lane];
    int wstart = blockIdx.x * 4 + wid, wstride = gridDim.x * 4;
    for (int v = wstart; v < n; v += wstride) {
        uint hv = H[(size_t)v * 64 + lane];
        float dv = rsqrtf((float)cnt[v] + 1.0f);
        float ap0 = 0.f, ap1 = 0.f, an0 = 0.f, an1 = 0.f;
#pragma unroll
        for (int k = 0; k < 64; k += 2) {
            uint u0 = __builtin_amdgcn_readlane(hv, k);
            uint u1 = __builtin_amdgcn_readlane(hv, k + 1);
            ap0 = fmaf(posf(u0), w[k], ap0);     an0 = fmaf(negf(u0), w[k], an0);
            ap1 = fmaf(posf(u1), w[k + 1], ap1); an1 = fmaf(negf(u1), w[k + 1], an1);
        }
        out[(size_t)v * 64 + lane] = packbf((ap0 + ap1) * dv, (an0 + an1) * dv);
    }
}

// ---- fused GCN aggregation, packed pos/neg (wave/node, lane=dim) ----------
// g pre-scaled by dis:  res = dv*(sum_in g[r] + g[v]) + bias
// MODE 0: relu -> out.  MODE 1: raw -> out, pos col-partials -> colpart.
template <int MODE>
__global__ __launch_bounds__(256) void conv_packed(
        const uint* __restrict__ g, const int* __restrict__ bucket,
        const int* __restrict__ cnt, const float* __restrict__ bias,
        uint* __restrict__ out, float* __restrict__ colpart, int n) {
    int lane = threadIdx.x & 63, wid = threadIdx.x >> 6;
    __shared__ float s[256];
    float colp  = 0.f;
    float blane = bias[lane];
    int wstart = blockIdx.x * 4 + wid, wstride = gridDim.x * 4;
    for (int v = wstart; v < n; v += wstride) {
        int cf = cnt[v];
        int c  = cf > CAP ? CAP : cf;
        float dv = rsqrtf((float)cf + 1.0f);
        size_t vo = (size_t)v * 64 + lane;
        uint su = g[vo];
        float a0p = posf(su), a1p = 0.f, a2p = 0.f, a3p = 0.f;   // self in a0
        float a0n = negf(su), a1n = 0.f, a2n = 0.f, a3n = 0.f;
        const int*  bk  = bucket + (size_t)v * CAP;
        const int4* bk4 = (const int4*)bk;
        int nq8 = c >> 3;
        for (int q = 0; q < nq8; q++) {
            int4 ra = bk4[2 * q], rb = bk4[2 * q + 1];
            uint u0 = g[(size_t)ra.x * 64 + lane];
            uint u1 = g[(size_t)ra.y * 64 + lane];
            uint u2 = g[(size_t)ra.z * 64 + lane];
            uint u3 = g[(size_t)ra.w * 64 + lane];
            uint u4 = g[(size_t)rb.x * 64 + lane];
            uint u5 = g[(size_t)rb.y * 64 + lane];
            uint u6 = g[(size_t)rb.z * 64 + lane];
            uint u7 = g[(size_t)rb.w * 64 + lane];
            a0p += posf(u0) + posf(u4); a0n += negf(u0) + negf(u4);
            a1p += posf(u1) + posf(u5); a1n += negf(u1) + negf(u5);
            a2p += posf(u2) + posf(u6); a2n += negf(u2) + negf(u6);
            a3p += posf(u3) + posf(u7); a3n += negf(u3) + negf(u7);
        }
        int i = nq8 << 3;
        if (c - i >= 4) {
            int4 r = bk4[i >> 2];
            uint u0 = g[(size_t)r.x * 64 + lane];
            uint u1 = g[(size_t)r.y * 64 + lane];
            uint u2 = g[(size_t)r.z * 64 + lane];
            uint u3 = g[(size_t)r.w * 64 + lane];
            a0p += posf(u0); a0n += negf(u0);
            a1p += posf(u1); a1n += negf(u1);
            a2p += posf(u2); a2n += negf(u2);
            a3p += posf(u3); a3n += negf(u3);
            i += 4;
        }
        for (; i < c; i++) {
            uint u = g[(size_t)bk[i] * 64 + lane];
            a0p += posf(u);
            a0n += negf(u);
        }
        float sp = (a0p + a1p) + (a2p + a3p);
        float sn = (a0n + a1n) + (a2n + a3n);
        float rp = fmaf(dv, sp, blane);
        float rn = fmaf(dv, sn, blane);
        if (MODE == 0) {
            out[vo] = packbf(fmaxf(rp, 0.f), fmaxf(rn, 0.f));
        } else {
            out[vo] = packbf(rp, rn);
            colp += rp;           // f32 partial (pre-rounding) for summary
        }
    }
    if (MODE == 1) {
        s[wid * 64 + lane] = colp;
        __syncthreads();
        if (wid == 0) {
            float t = s[lane] + s[64 + lane] + s[128 + lane] + s[192 + lane];
            colpart[(size_t)blockIdx.x * 64 + lane] = t;
        }
    }
}

// ---- stage A: sum RB colpart rows per block -> colpart2 (GG/RB rows) ------
__global__ __launch_bounds__(256) void colreduce_kernel(
        const float* __restrict__ colpart, float* __restrict__ colpart2) {
    int lane = threadIdx.x & 63, w = threadIdx.x >> 6;
    __shared__ float s4[4][64];
    float t = 0.f;
    int base = blockIdx.x * RB;
    for (int g = w; g < RB; g += 4) t += colpart[(size_t)(base + g) * 64 + lane];
    s4[w][lane] = t;
    __syncthreads();
    if (w == 0)
        colpart2[(size_t)blockIdx.x * 64 + lane] =
            s4[0][lane] + s4[1][lane] + s4[2][lane] + s4[3][lane];
}

// ---- summary + ws = W_dgi @ sigmoid(mean(pos_z)) --------------------------
__global__ void summary_kernel(const float* __restrict__ colpart,
                               const float* __restrict__ Wdgi,
                               float* __restrict__ wsv, int G, float invN) {
    __shared__ float sm[64];
    __shared__ float s4[4][64];
    int lane = threadIdx.x & 63, w = threadIdx.x >> 6;
    float t = 0.f;
    for (int g = w; g < G; g += 4) t += colpart[(size_t)g * 64 + lane];
    s4[w][lane] = t;
    __syncthreads();
    if (w == 0) {
        t = s4[0][lane] + s4[1][lane] + s4[2][lane] + s4[3][lane];
        sm[lane] = 1.f / (1.f + expf(-t * invN));
    }
    __syncthreads();
    if (threadIdx.x < 64) {
        float a = 0.f;
        for (int j = 0; j < 64; j++) a += Wdgi[threadIdx.x * 64 + j] * sm[j];
        wsv[threadIdx.x] = a;
    }
}

// ---- both losses in one pass (packed z) -----------------------------------
__global__ __launch_bounds__(256) void loss_kernel(
        const uint* __restrict__ z, const float* __restrict__ wsv,
        float* __restrict__ lossacc, int n) {
    int lane = threadIdx.x & 63, wid = threadIdx.x >> 6;
    __shared__ float s[16];
    float wlane = wsv[lane];
    float lp = 0.f, ln = 0.f;
    int wstart = blockIdx.x * 4 + wid, wstride = gridDim.x * 4;
    for (int v = wstart; v < n; v += wstride) {
        uint u = z[(size_t)v * 64 + lane];
        float p = posf(u) * wlane;
        float q = negf(u) * wlane;
        for (int off = 32; off; off >>= 1) {
            p += __shfl_xor(p, off, 64);
            q += __shfl_xor(q, off, 64);
        }
        if (lane == 0) {
            lp += -logf(1.f / (1.f + expf(-p)) + 1e-15f);   // -log(sigmoid(p)+eps)
            ln += -logf(1.f / (1.f + expf( q)) + 1e-15f);   // -log(1-sigmoid(q)+eps)
        }
    }
    if (lane == 0) { s[wid] = lp; s[8 + wid] = ln; }
    __syncthreads();
    if (threadIdx.x == 0) atomicAdd(&lossacc[0], s[0] + s[1] + s[2] + s[3]);
    if (threadIdx.x == 1) atomicAdd(&lossacc[1], s[8] + s[9] + s[10] + s[11]);
}

__global__ void finalize_kernel(const float* __restrict__ lossacc,
                                float* __restrict__ out, float invN) {
    out[0] = (lossacc[0] + lossacc[1]) * invN;
}

// ---------------------------------------------------------------------------
extern "C" void kernel_launch(void* const* d_in, const int* in_sizes, int n_in,
                              void* d_out, int out_size, void* d_ws, size_t ws_size,
                              hipStream_t stream) {
    const float* x    = (const float*)d_in[0];
    const float* W1   = (const float*)d_in[1];
    const float* b1   = (const float*)d_in[2];
    const float* W2   = (const float*)d_in[3];
    const float* b2   = (const float*)d_in[4];
    const float* Wdgi = (const float*)d_in[5];
    const int*   edge = (const int*)d_in[6];
    const int*   perm = (const int*)d_in[7];

    const int N = in_sizes[7];
    const int E = in_sizes[6] / 2;
    const int* row = edge;
    const int* col = edge + E;

    char* wsb = (char*)d_ws;
    size_t off = 0;
    auto alloc = [&](size_t bytes) -> void* {
        void* p = wsb + off;
        off = (off + bytes + 255) & ~(size_t)255;
        return p;
    };
    int*   bucket   = (int*)  alloc((size_t)N * CAP * 4);   // 25.6 MB
    int*   cnt      = (int*)  alloc((size_t)N * 4);
    uint*  G        = (uint*) alloc((size_t)N * 64 * 4);    // packed pos/neg, 25.6 MB
    uint*  H        = (uint*) alloc((size_t)N * 64 * 4);
    float* colpart  = (float*)alloc((size_t)GG * 64 * 4);
    float* colpart2 = (float*)alloc((size_t)(GG / RB) * 64 * 4);
    float* wsv      = (float*)alloc(64 * 4);
    float* lossacc  = (float*)alloc(2 * 4);

    hipMemsetAsync(cnt, 0, (size_t)N * 4, stream);
    hipMemsetAsync(lossacc, 0, 8, stream);

    const int bound = (N + 7) / 8;   // col-range per XCD group
    place_grouped<<<1024, 256, 0, stream>>>(row, col, bucket, cnt, E, bound);

    // layer 1: G = (X @ W1) * dis (both branches packed), aggregate+relu -> H
    gemm1_both<<<1024, 256, 0, stream>>>(x, W1, perm, cnt, G, N);
    conv_packed<0><<<GG, 256, 0, stream>>>(G, bucket, cnt, b1, H, nullptr, N);
    // layer 2: G = (H @ W2) * dis, aggregate -> z (in H) + colpart
    gemm2_both<<<1024, 256, 0, stream>>>(H, W2, cnt, G, N);
    conv_packed<1><<<GG, 256, 0, stream>>>(G, bucket, cnt, b2, H, colpart, N);

    colreduce_kernel<<<GG / RB, 256, 0, stream>>>(colpart, colpart2);
    summary_kernel<<<1, 256, 0, stream>>>(colpart2, Wdgi, wsv, GG / RB, 1.0f / N);
    loss_kernel<<<1024, 256, 0, stream>>>(H, wsv, lossacc, N);
    finalize_kernel<<<1, 1, 0, stream>>>(lossacc, (float*)d_out, 1.0f / N);
}